// Round 14
// baseline (213.912 us; speedup 1.0000x reference)
//
#include <hip/hip_runtime.h>

typedef __bf16 bf16;
typedef __bf16 bf16x4 __attribute__((ext_vector_type(4)));
typedef __bf16 bf16x8 __attribute__((ext_vector_type(8)));
typedef float f32x4 __attribute__((ext_vector_type(4)));
typedef float f32x16 __attribute__((ext_vector_type(16)));

#define DIMD 1024
#define NHEAD 16
#define HDIM 64
#define BATCH 2
#define SEQ 2048
#define MTOT (BATCH*SEQ)   // 4096

#define EXP2F(x) __builtin_amdgcn_exp2f(x)

// ---- memory plan (total ws use = 16 MB) ----
// d_out: [0,8MB) Qb bf16 [32][2048][64] (pre-scaled 0.125*log2e); [8,16MB) Kb
// d_ws:  [0,8MB) xb bf16 [4096][1024] -> dead after QKV GEMM, then Ob
//        [8,16MB) Vt bf16 [32][64][2048]
#define OFF_XB (0ull)
#define OFF_OB (0ull)
#define OFF_VT (8ull<<20)

__device__ __forceinline__ void g2l16(const void* g, void* l) {
  __builtin_amdgcn_global_load_lds(
      (const __attribute__((address_space(1))) void*)g,
      (__attribute__((address_space(3))) void*)l,
      16, 0, 0);
}

__device__ __forceinline__ bf16x8 cvt8(float4 a, float4 b) {
  bf16x8 r = { (bf16)a.x, (bf16)a.y, (bf16)a.z, (bf16)a.w,
               (bf16)b.x, (bf16)b.y, (bf16)b.z, (bf16)b.w };
  return r;
}

// ---------------- fp32 -> bf16 conversion ----------------
__global__ __launch_bounds__(256) void cvt_kernel(const float* __restrict__ in,
                                                  bf16* __restrict__ out, int n4) {
  int i = blockIdx.x * blockDim.x + threadIdx.x;
  if (i < n4) {
    float4 v = ((const float4*)in)[i];
    bf16x4 o = { (bf16)v.x, (bf16)v.y, (bf16)v.z, (bf16)v.w };
    ((bf16x4*)out)[i] = o;
  }
}

// ---------------- QKV GEMM (unchanged from R13) ----------------
__global__ __launch_bounds__(256, 3) void gemm_qkv(
    const bf16* __restrict__ A, const float* __restrict__ W,
    const float* __restrict__ bias,
    bf16* __restrict__ Qb, bf16* __restrict__ Kb, bf16* __restrict__ Vt)
{
  __shared__ bf16 lA[2][128 * 32];
  __shared__ bf16 lB[2][128 * 32];
  const int tid = threadIdx.x;
  const int wave = tid >> 6, lane = tid & 63;
  const int l15 = lane & 15, quad = lane >> 4;
  const int wm = wave >> 1, wn = wave & 1;
  const int tm = blockIdx.y * 128, tn = blockIdx.x * 128;

  f32x4 acc[4][4] = {};

  const int srow = tid >> 2, sch = (tid & 3) * 8;
  const bf16*  ga = &A[(size_t)(tm + srow) * DIMD + sch];
  const float* gb = &W[(size_t)(tn + srow) * DIMD + sch];

  g2l16(ga,                     &lA[0][wave * 512]);
  g2l16(ga + (size_t)64 * DIMD, &lA[0][2048 + wave * 512]);
  float4 bv0 = ((const float4*)gb)[0], bv1 = ((const float4*)gb)[1];
  float4 bv2 = ((const float4*)(gb + (size_t)64 * DIMD))[0],
         bv3 = ((const float4*)(gb + (size_t)64 * DIMD))[1];

  for (int kt = 0; kt < 32; kt++) {
    bf16* sB = lB[kt & 1];
    *(bf16x8*)&sB[srow * 32 + sch]        = cvt8(bv0, bv1);
    *(bf16x8*)&sB[(64 + srow) * 32 + sch] = cvt8(bv2, bv3);
    __syncthreads();

    if (kt < 31) {
      const int kn = (kt + 1) * 32;
      bf16* nA = lA[(kt + 1) & 1];
      g2l16(ga + kn,                     &nA[wave * 512]);
      g2l16(ga + kn + (size_t)64 * DIMD, &nA[2048 + wave * 512]);
      const float* gbn = gb + kn;
      bv0 = ((const float4*)gbn)[0]; bv1 = ((const float4*)gbn)[1];
      bv2 = ((const float4*)(gbn + (size_t)64 * DIMD))[0];
      bv3 = ((const float4*)(gbn + (size_t)64 * DIMD))[1];
    }

    const bf16* sA = lA[kt & 1];
    bf16x8 af[4], bfr[4];
#pragma unroll
    for (int i = 0; i < 4; i++)
      af[i] = *(const bf16x8*)&sA[(wm * 64 + i * 16 + l15) * 32 + quad * 8];
#pragma unroll
    for (int i = 0; i < 4; i++)
      bfr[i] = *(const bf16x8*)&sB[(wn * 64 + i * 16 + l15) * 32 + quad * 8];
#pragma unroll
    for (int i = 0; i < 4; i++)
#pragma unroll
      for (int j = 0; j < 4; j++)
        acc[i][j] = __builtin_amdgcn_mfma_f32_16x16x32_bf16(af[i], bfr[j], acc[i][j], 0, 0, 0);
  }

  const int sel = tn >> 10;  // 0=Q 1=K 2=V
#pragma unroll
  for (int j = 0; j < 4; j++) {
    const int n = tn + wn * 64 + j * 16 + l15;
    const float bv = bias[n];
    const int d = n & 1023, h = d >> 6, hd = d & 63;
#pragma unroll
    for (int i = 0; i < 4; i++) {
      const int mbase = tm + wm * 64 + i * 16 + quad * 4;
      const int b = mbase >> 11, s0 = mbase & 2047;
      const int bh = b * NHEAD + h;
      if (sel == 2) {
        bf16x4 vv = { (bf16)(acc[i][j][0] + bv), (bf16)(acc[i][j][1] + bv),
                      (bf16)(acc[i][j][2] + bv), (bf16)(acc[i][j][3] + bv) };
        *(bf16x4*)&Vt[((size_t)bh * HDIM + hd) * SEQ + s0] = vv;
      } else {
#pragma unroll
        for (int r = 0; r < 4; r++) {
          float v = acc[i][j][r] + bv;
          if (sel == 0)
            Qb[((size_t)bh * SEQ + s0 + r) * HDIM + hd] = (bf16)(v * 0.18033688f); // 0.125*log2e
          else
            Kb[((size_t)bh * SEQ + s0 + r) * HDIM + hd] = (bf16)v;
        }
      }
    }
  }
}

// ---------------- proj GEMM (unchanged from R13) ----------------
__global__ __launch_bounds__(256, 2) void gemm_proj(
    const bf16* __restrict__ A, const float* __restrict__ W,
    const float* __restrict__ bias, float* __restrict__ out)
{
  __shared__ bf16 lA[2][64 * 32];
  __shared__ bf16 lB[2][128 * 32];
  const int tid = threadIdx.x;
  const int wave = tid >> 6, lane = tid & 63;
  const int l15 = lane & 15, quad = lane >> 4;
  const int tm = blockIdx.y * 64, tn = blockIdx.x * 128;

  f32x4 acc[4][2] = {};

  const int srow = tid >> 2, sch = (tid & 3) * 8;
  const bf16*  ga = &A[(size_t)(tm + srow) * DIMD + sch];
  const float* gb = &W[(size_t)(tn + srow) * DIMD + sch];

  g2l16(ga, &lA[0][wave * 512]);
  float4 bv0 = ((const float4*)gb)[0], bv1 = ((const float4*)gb)[1];
  float4 bv2 = ((const float4*)(gb + (size_t)64 * DIMD))[0],
         bv3 = ((const float4*)(gb + (size_t)64 * DIMD))[1];

  for (int kt = 0; kt < 32; kt++) {
    bf16* sB = lB[kt & 1];
    *(bf16x8*)&sB[srow * 32 + sch]        = cvt8(bv0, bv1);
    *(bf16x8*)&sB[(64 + srow) * 32 + sch] = cvt8(bv2, bv3);
    __syncthreads();

    if (kt < 31) {
      const int kn = (kt + 1) * 32;
      g2l16(ga + kn, &lA[(kt + 1) & 1][wave * 512]);
      const float* gbn = gb + kn;
      bv0 = ((const float4*)gbn)[0]; bv1 = ((const float4*)gbn)[1];
      bv2 = ((const float4*)(gbn + (size_t)64 * DIMD))[0];
      bv3 = ((const float4*)(gbn + (size_t)64 * DIMD))[1];
    }

    const bf16* sA = lA[kt & 1];
    bf16x8 af[4], bfr[2];
#pragma unroll
    for (int i = 0; i < 4; i++)
      af[i] = *(const bf16x8*)&sA[(i * 16 + l15) * 32 + quad * 8];
#pragma unroll
    for (int j = 0; j < 2; j++)
      bfr[j] = *(const bf16x8*)&sB[(wave * 32 + j * 16 + l15) * 32 + quad * 8];
#pragma unroll
    for (int i = 0; i < 4; i++)
#pragma unroll
      for (int j = 0; j < 2; j++)
        acc[i][j] = __builtin_amdgcn_mfma_f32_16x16x32_bf16(af[i], bfr[j], acc[i][j], 0, 0, 0);
  }

#pragma unroll
  for (int j = 0; j < 2; j++) {
    const int n = tn + wave * 32 + j * 16 + l15;
    const float bv = bias[n];
#pragma unroll
    for (int i = 0; i < 4; i++) {
      const int mbase = tm + i * 16 + quad * 4;
#pragma unroll
      for (int r = 0; r < 4; r++)
        out[(size_t)(mbase + r) * DIMD + n] = acc[i][j][r] + bv;
    }
  }
}

// ---------------- flash attention v9 ----------------
// Double-buffered KV (static kt&1 addressing -> compiler unrolls by 2, all
// LDS offsets immediate) + V fragments copied LDS->regs each iter (vnew);
// PV(t-1) consumes vold REGISTERS + wave-private lP, never the KV buffers,
// so staging may overwrite freely: race-free with 2 buffers.
// All buf[t&1] reads (K frags, V->reg) sit between barrier(t) and this
// wave's staging(t+1); any rewrite of buf[t&1] is staging(t+2), behind
// barrier(t+1). No-max exp2 softmax (logits bounded; R12/R13-verified).
#define LSTR 72
#define PSTR 68
__global__ __launch_bounds__(256, 2) void attn_kernel(
    const bf16* __restrict__ Qb, const bf16* __restrict__ Kb,
    const bf16* __restrict__ Vt, bf16* __restrict__ Ob)
{
  __shared__ bf16 lKV[2][2][64 * LSTR];   // [buf][K=0/V=1]
  __shared__ bf16 lP[4][32 * PSTR];

  const int tid = threadIdx.x;
  const int wave = tid >> 6, lane = tid & 63;
  const int l31 = lane & 31, h = lane >> 5;
  const int xcd = blockIdx.x & 7, grp = blockIdx.x >> 3;
  const int bh = xcd + 8 * (grp & 3);
  const int qt = grp >> 2;

  const int qrow = qt * 128 + wave * 32 + l31;
  const bf16* qp = Qb + ((size_t)bh * SEQ + qrow) * HDIM + h * 8;
  bf16x8 qf[4];
#pragma unroll
  for (int c = 0; c < 4; c++) qf[c] = *(const bf16x8*)(qp + c * 16);

  const int srow = tid >> 3;            // 0..31
  const int sch = (tid & 7) * 8;        // bf16 elem offset in 64
  const bf16* kg = Kb + ((size_t)bh * SEQ + srow) * HDIM + sch;
  const bf16* vg = Vt + ((size_t)bh * HDIM + srow) * SEQ + sch;

  uint4 kr0 = *(const uint4*)(kg);
  uint4 kr1 = *(const uint4*)(kg + 32 * HDIM);
  uint4 vr0 = *(const uint4*)(vg);
  uint4 vr1 = *(const uint4*)(vg + 32 * SEQ);

  bf16* pw = lP[wave];

  f32x16 o0 = {}, o1 = {};
  float lsum = 0.f;
  bf16x8 vold0[4], vold1[4];            // V(t-1) fragments, register-resident

  for (int kt = 0; kt < SEQ / 64; kt++) {
    // stage tile kt into buf[kt&1]
    bf16* sK = lKV[kt & 1][0];
    bf16* sV = lKV[kt & 1][1];
    *(uint4*)&sK[srow * LSTR + sch]        = kr0;
    *(uint4*)&sK[(32 + srow) * LSTR + sch] = kr1;
    *(uint4*)&sV[srow * LSTR + sch]        = vr0;
    *(uint4*)&sV[(32 + srow) * LSTR + sch] = vr1;
    __syncthreads();

    // prefetch tile kt+1 from global (wraps on last iter; harmless)
    const int ktn = (kt + 1) & (SEQ / 64 - 1);
    kr0 = *(const uint4*)(kg + (size_t)ktn * 64 * HDIM);
    kr1 = *(const uint4*)(kg + (size_t)ktn * 64 * HDIM + 32 * HDIM);
    vr0 = *(const uint4*)(vg + ktn * 64);
    vr1 = *(const uint4*)(vg + ktn * 64 + 32 * SEQ);

    // V(t) frags LDS->regs (consumed by PV at iter t+1)
    bf16x8 vnew0[4], vnew1[4];
#pragma unroll
    for (int c = 0; c < 4; c++) {
      vnew0[c] = *(const bf16x8*)&sV[l31 * LSTR + c * 16 + h * 8];
      vnew1[c] = *(const bf16x8*)&sV[(32 + l31) * LSTR + c * 16 + h * 8];
    }

    // S^T(t) = K Q^T
    f32x16 s0 = {}, s1 = {};
#pragma unroll
    for (int c = 0; c < 4; c++) {
      bf16x8 k0 = *(const bf16x8*)&sK[l31 * LSTR + c * 16 + h * 8];
      bf16x8 k1 = *(const bf16x8*)&sK[(32 + l31) * LSTR + c * 16 + h * 8];
      s0 = __builtin_amdgcn_mfma_f32_32x32x16_bf16(k0, qf[c], s0, 0, 0, 0);
      s1 = __builtin_amdgcn_mfma_f32_32x32x16_bf16(k1, qf[c], s1, 0, 0, 0);
    }

    // PV(t-1): vold regs + lP (wave-private) — no KV-buffer access
    if (kt > 0) {
#pragma unroll
      for (int c = 0; c < 4; c++) {
        bf16x8 pf = *(const bf16x8*)&pw[l31 * PSTR + c * 16 + h * 8];
        o0 = __builtin_amdgcn_mfma_f32_32x32x16_bf16(vold0[c], pf, o0, 0, 0, 0);
        o1 = __builtin_amdgcn_mfma_f32_32x32x16_bf16(vold1[c], pf, o1, 0, 0, 0);
      }
    }

    // P = exp2(S) (no shift; logits bounded), local l accumulation
#pragma unroll
    for (int r = 0; r < 16; r++) {
      const float p0 = EXP2F(s0[r]);
      const float p1 = EXP2F(s1[r]);
      s0[r] = p0; s1[r] = p1;
      lsum += p0 + p1;
    }

    // write P(t) for PV at iter t+1 (wave-private, DS in-order)
#pragma unroll
    for (int g = 0; g < 4; g++) {
      bf16x4 pa = { (bf16)s0[4*g], (bf16)s0[4*g+1], (bf16)s0[4*g+2], (bf16)s0[4*g+3] };
      bf16x4 pb = { (bf16)s1[4*g], (bf16)s1[4*g+1], (bf16)s1[4*g+2], (bf16)s1[4*g+3] };
      *(bf16x4*)&pw[l31 * PSTR + g * 8 + h * 4]      = pa;
      *(bf16x4*)&pw[l31 * PSTR + 32 + g * 8 + h * 4] = pb;
    }

#pragma unroll
    for (int c = 0; c < 4; c++) { vold0[c] = vnew0[c]; vold1[c] = vnew1[c]; }
  }

  // drain: PV(31)
  {
#pragma unroll
    for (int c = 0; c < 4; c++) {
      bf16x8 pf = *(const bf16x8*)&pw[l31 * PSTR + c * 16 + h * 8];
      o0 = __builtin_amdgcn_mfma_f32_32x32x16_bf16(vold0[c], pf, o0, 0, 0, 0);
      o1 = __builtin_amdgcn_mfma_f32_32x32x16_bf16(vold1[c], pf, o1, 0, 0, 0);
    }
  }

  // l = this lane's 32-key sum + the other half from lane^32 (same q-row)
  const float lrow = lsum + __shfl_xor(lsum, 32, 64);
  const int b = bh >> 4, head = bh & 15;
  const float inv = 1.f / lrow;
  const size_t base = ((size_t)b * SEQ + qrow) * DIMD + head * HDIM;
#pragma unroll
  for (int g = 0; g < 4; g++) {
    bf16x4 oa = { (bf16)(o0[4*g] * inv), (bf16)(o0[4*g+1] * inv),
                  (bf16)(o0[4*g+2] * inv), (bf16)(o0[4*g+3] * inv) };
    bf16x4 ob = { (bf16)(o1[4*g] * inv), (bf16)(o1[4*g+1] * inv),
                  (bf16)(o1[4*g+2] * inv), (bf16)(o1[4*g+3] * inv) };
    *(bf16x4*)&Ob[base + g * 8 + h * 4]      = oa;
    *(bf16x4*)&Ob[base + 32 + g * 8 + h * 4] = ob;
  }
}

extern "C" void kernel_launch(void* const* d_in, const int* in_sizes, int n_in,
                              void* d_out, int out_size, void* d_ws, size_t ws_size,
                              hipStream_t stream) {
  const float* x      = (const float*)d_in[0];
  const float* w_qkv  = (const float*)d_in[1];
  const float* b_qkv  = (const float*)d_in[2];
  const float* w_proj = (const float*)d_in[3];
  const float* b_proj = (const float*)d_in[4];
  float* out = (float*)d_out;
  char* ws = (char*)d_ws;

  bf16* Qb = (bf16*)d_out;
  bf16* Kb = (bf16*)d_out + (size_t)MTOT * DIMD;
  bf16* xb = (bf16*)(ws + OFF_XB);
  bf16* Ob = (bf16*)(ws + OFF_OB);   // overlays xb (dead after QKV GEMM)
  bf16* Vt = (bf16*)(ws + OFF_VT);

  cvt_kernel<<<(MTOT * DIMD / 4) / 256, 256, 0, stream>>>(x, xb, MTOT * DIMD / 4);
  gemm_qkv<<<dim3(24, 32), 256, 0, stream>>>(xb, w_qkv, b_qkv, Qb, Kb, Vt);
  attn_kernel<<<BATCH * NHEAD * (SEQ / 128), 256, 0, stream>>>(Qb, Kb, Vt, Ob);
  gemm_proj<<<dim3(8, 64), 256, 0, stream>>>(Ob, w_proj, b_proj, out);
}

// Round 15
// 192.024 us; speedup vs baseline: 1.1140x; 1.1140x over previous
//
#include <hip/hip_runtime.h>

typedef __bf16 bf16;
typedef __bf16 bf16x4 __attribute__((ext_vector_type(4)));
typedef __bf16 bf16x8 __attribute__((ext_vector_type(8)));
typedef float f32x4 __attribute__((ext_vector_type(4)));
typedef float f32x16 __attribute__((ext_vector_type(16)));

#define DIMD 1024
#define NHEAD 16
#define HDIM 64
#define BATCH 2
#define SEQ 2048
#define MTOT (BATCH*SEQ)   // 4096

#define EXP2F(x) __builtin_amdgcn_exp2f(x)

// ---- memory plan (total ws use = 16 MB) ----
// d_out: [0,8MB) Qb bf16 (pre-scaled 0.125*log2e); [8,16MB) Kb   (dead after attn -> out)
// d_ws:  [0,8MB) xb bf16 -> dead after QKV GEMM, then Ob
//        [8,16MB) Vt bf16 -> dead after attn, then wprojb bf16 (2MB)
#define OFF_XB (0ull)
#define OFF_OB (0ull)
#define OFF_VT (8ull<<20)
#define OFF_WP (8ull<<20)

__device__ __forceinline__ void g2l16(const void* g, void* l) {
  __builtin_amdgcn_global_load_lds(
      (const __attribute__((address_space(1))) void*)g,
      (__attribute__((address_space(3))) void*)l,
      16, 0, 0);
}

__device__ __forceinline__ bf16x8 cvt8(float4 a, float4 b) {
  bf16x8 r = { (bf16)a.x, (bf16)a.y, (bf16)a.z, (bf16)a.w,
               (bf16)b.x, (bf16)b.y, (bf16)b.z, (bf16)b.w };
  return r;
}

// ---------------- fp32 -> bf16 conversion ----------------
__global__ __launch_bounds__(256) void cvt_kernel(const float* __restrict__ in,
                                                  bf16* __restrict__ out, int n4) {
  int i = blockIdx.x * blockDim.x + threadIdx.x;
  if (i < n4) {
    float4 v = ((const float4*)in)[i];
    bf16x4 o = { (bf16)v.x, (bf16)v.y, (bf16)v.z, (bf16)v.w };
    ((bf16x4*)out)[i] = o;
  }
}

// ---------------- QKV GEMM (unchanged — R9/R10 proven) ----------------
__global__ __launch_bounds__(256, 3) void gemm_qkv(
    const bf16* __restrict__ A, const float* __restrict__ W,
    const float* __restrict__ bias,
    bf16* __restrict__ Qb, bf16* __restrict__ Kb, bf16* __restrict__ Vt)
{
  __shared__ bf16 lA[2][128 * 32];
  __shared__ bf16 lB[2][128 * 32];
  const int tid = threadIdx.x;
  const int wave = tid >> 6, lane = tid & 63;
  const int l15 = lane & 15, quad = lane >> 4;
  const int wm = wave >> 1, wn = wave & 1;
  const int tm = blockIdx.y * 128, tn = blockIdx.x * 128;

  f32x4 acc[4][4] = {};

  const int srow = tid >> 2, sch = (tid & 3) * 8;
  const bf16*  ga = &A[(size_t)(tm + srow) * DIMD + sch];
  const float* gb = &W[(size_t)(tn + srow) * DIMD + sch];

  g2l16(ga,                     &lA[0][wave * 512]);
  g2l16(ga + (size_t)64 * DIMD, &lA[0][2048 + wave * 512]);
  float4 bv0 = ((const float4*)gb)[0], bv1 = ((const float4*)gb)[1];
  float4 bv2 = ((const float4*)(gb + (size_t)64 * DIMD))[0],
         bv3 = ((const float4*)(gb + (size_t)64 * DIMD))[1];

  for (int kt = 0; kt < 32; kt++) {
    bf16* sB = lB[kt & 1];
    *(bf16x8*)&sB[srow * 32 + sch]        = cvt8(bv0, bv1);
    *(bf16x8*)&sB[(64 + srow) * 32 + sch] = cvt8(bv2, bv3);
    __syncthreads();

    if (kt < 31) {
      const int kn = (kt + 1) * 32;
      bf16* nA = lA[(kt + 1) & 1];
      g2l16(ga + kn,                     &nA[wave * 512]);
      g2l16(ga + kn + (size_t)64 * DIMD, &nA[2048 + wave * 512]);
      const float* gbn = gb + kn;
      bv0 = ((const float4*)gbn)[0]; bv1 = ((const float4*)gbn)[1];
      bv2 = ((const float4*)(gbn + (size_t)64 * DIMD))[0];
      bv3 = ((const float4*)(gbn + (size_t)64 * DIMD))[1];
    }

    const bf16* sA = lA[kt & 1];
    bf16x8 af[4], bfr[4];
#pragma unroll
    for (int i = 0; i < 4; i++)
      af[i] = *(const bf16x8*)&sA[(wm * 64 + i * 16 + l15) * 32 + quad * 8];
#pragma unroll
    for (int i = 0; i < 4; i++)
      bfr[i] = *(const bf16x8*)&sB[(wn * 64 + i * 16 + l15) * 32 + quad * 8];
#pragma unroll
    for (int i = 0; i < 4; i++)
#pragma unroll
      for (int j = 0; j < 4; j++)
        acc[i][j] = __builtin_amdgcn_mfma_f32_16x16x32_bf16(af[i], bfr[j], acc[i][j], 0, 0, 0);
  }

  const int sel = tn >> 10;  // 0=Q 1=K 2=V
#pragma unroll
  for (int j = 0; j < 4; j++) {
    const int n = tn + wn * 64 + j * 16 + l15;
    const float bv = bias[n];
    const int d = n & 1023, h = d >> 6, hd = d & 63;
#pragma unroll
    for (int i = 0; i < 4; i++) {
      const int mbase = tm + wm * 64 + i * 16 + quad * 4;
      const int b = mbase >> 11, s0 = mbase & 2047;
      const int bh = b * NHEAD + h;
      if (sel == 2) {
        bf16x4 vv = { (bf16)(acc[i][j][0] + bv), (bf16)(acc[i][j][1] + bv),
                      (bf16)(acc[i][j][2] + bv), (bf16)(acc[i][j][3] + bv) };
        *(bf16x4*)&Vt[((size_t)bh * HDIM + hd) * SEQ + s0] = vv;
      } else {
#pragma unroll
        for (int r = 0; r < 4; r++) {
          float v = acc[i][j][r] + bv;
          if (sel == 0)
            Qb[((size_t)bh * SEQ + s0 + r) * HDIM + hd] = (bf16)(v * 0.18033688f); // 0.125*log2e
          else
            Kb[((size_t)bh * SEQ + s0 + r) * HDIM + hd] = (bf16)v;
        }
      }
    }
  }
}

// ---------------- proj GEMM v2: both operands async via global_load_lds ----
// Single-barrier K-loop, zero-VALU staging: barrier(t) drains g2l16(t);
// g2l16(t+1) issued right after and flies for the whole compute body.
// A = Ob bf16, B = wprojb bf16 (pre-converted into the dead Vt region).
__global__ __launch_bounds__(256, 2) void gemm_proj(
    const bf16* __restrict__ A, const bf16* __restrict__ Bt,
    const float* __restrict__ bias, float* __restrict__ out)
{
  __shared__ bf16 lA[2][64 * 32];
  __shared__ bf16 lB[2][128 * 32];
  const int tid = threadIdx.x;
  const int wave = tid >> 6, lane = tid & 63;
  const int l15 = lane & 15, quad = lane >> 4;
  const int tm = blockIdx.y * 64, tn = blockIdx.x * 128;

  f32x4 acc[4][2] = {};

  const int srow = tid >> 2, sch = (tid & 3) * 8;
  const bf16* ga = &A[(size_t)(tm + srow) * DIMD + sch];
  const bf16* gb = &Bt[(size_t)(tn + srow) * DIMD + sch];

  g2l16(ga,                     &lA[0][wave * 512]);
  g2l16(gb,                     &lB[0][wave * 512]);
  g2l16(gb + (size_t)64 * DIMD, &lB[0][2048 + wave * 512]);

  for (int kt = 0; kt < 32; kt++) {
    __syncthreads();   // drains g2l16(t); separates buf[(t+1)&1] rewrite from iter t-1 reads

    if (kt < 31) {
      const int kn = (kt + 1) * 32;
      bf16* nA = lA[(kt + 1) & 1];
      bf16* nB = lB[(kt + 1) & 1];
      g2l16(ga + kn,                     &nA[wave * 512]);
      g2l16(gb + kn,                     &nB[wave * 512]);
      g2l16(gb + kn + (size_t)64 * DIMD, &nB[2048 + wave * 512]);
    }

    const bf16* sA = lA[kt & 1];
    const bf16* sB = lB[kt & 1];
    bf16x8 af[4], bfr[2];
#pragma unroll
    for (int i = 0; i < 4; i++)
      af[i] = *(const bf16x8*)&sA[(i * 16 + l15) * 32 + quad * 8];
#pragma unroll
    for (int j = 0; j < 2; j++)
      bfr[j] = *(const bf16x8*)&sB[(wave * 32 + j * 16 + l15) * 32 + quad * 8];
#pragma unroll
    for (int i = 0; i < 4; i++)
#pragma unroll
      for (int j = 0; j < 2; j++)
        acc[i][j] = __builtin_amdgcn_mfma_f32_16x16x32_bf16(af[i], bfr[j], acc[i][j], 0, 0, 0);
  }

#pragma unroll
  for (int j = 0; j < 2; j++) {
    const int n = tn + wave * 32 + j * 16 + l15;
    const float bv = bias[n];
#pragma unroll
    for (int i = 0; i < 4; i++) {
      const int mbase = tm + i * 16 + quad * 4;
#pragma unroll
      for (int r = 0; r < 4; r++)
        out[(size_t)(mbase + r) * DIMD + n] = acc[i][j][r] + bv;
    }
  }
}

// ---------------- flash attention v6 (exact R10 revert — measured 58.4us) ----
#define LSTR 72
__global__ __launch_bounds__(256, 2) void attn_kernel(
    const bf16* __restrict__ Qb, const bf16* __restrict__ Kb,
    const bf16* __restrict__ Vt, bf16* __restrict__ Ob)
{
  __shared__ bf16 lKV[2][2][64 * LSTR];   // [buf][K=0/V=1]
  __shared__ bf16 lP[4][32 * LSTR];

  const int tid = threadIdx.x;
  const int wave = tid >> 6, lane = tid & 63;
  const int l31 = lane & 31, h = lane >> 5;
  const int xcd = blockIdx.x & 7, grp = blockIdx.x >> 3;
  const int bh = xcd + 8 * (grp & 3);
  const int qt = grp >> 2;

  const int qrow = qt * 128 + wave * 32 + l31;
  const bf16* qp = Qb + ((size_t)bh * SEQ + qrow) * HDIM + h * 8;
  bf16x8 qf[4];
#pragma unroll
  for (int c = 0; c < 4; c++) qf[c] = *(const bf16x8*)(qp + c * 16);

  const int srow = tid >> 3;            // 0..31
  const int sch = (tid & 7) * 8;        // bf16 elem offset in 64
  const bf16* kg = Kb + ((size_t)bh * SEQ + srow) * HDIM + sch;
  const bf16* vg = Vt + ((size_t)bh * HDIM + srow) * SEQ + sch;

  uint4 kr0 = *(const uint4*)(kg);
  uint4 kr1 = *(const uint4*)(kg + 32 * HDIM);
  uint4 vr0 = *(const uint4*)(vg);
  uint4 vr1 = *(const uint4*)(vg + 32 * SEQ);

  bf16* pw = lP[wave];

  f32x16 o0 = {}, o1 = {};
  float mrow = -1e30f, lrow = 0.f;

  for (int kt = 0; kt < SEQ / 64; kt++) {
    bf16* sK = lKV[kt & 1][0];
    bf16* sV = lKV[kt & 1][1];
    *(uint4*)&sK[srow * LSTR + sch]        = kr0;
    *(uint4*)&sK[(32 + srow) * LSTR + sch] = kr1;
    *(uint4*)&sV[srow * LSTR + sch]        = vr0;
    *(uint4*)&sV[(32 + srow) * LSTR + sch] = vr1;
    __syncthreads();

    const int ktn = (kt + 1) & (SEQ / 64 - 1);
    kr0 = *(const uint4*)(kg + (size_t)ktn * 64 * HDIM);
    kr1 = *(const uint4*)(kg + (size_t)ktn * 64 * HDIM + 32 * HDIM);
    vr0 = *(const uint4*)(vg + ktn * 64);
    vr1 = *(const uint4*)(vg + ktn * 64 + 32 * SEQ);

    // S^T(t) = K Q^T : issue first so softmax's dependency is in flight
    f32x16 s0 = {}, s1 = {};
#pragma unroll
    for (int c = 0; c < 4; c++) {
      bf16x8 k0 = *(const bf16x8*)&sK[l31 * LSTR + c * 16 + h * 8];
      bf16x8 k1 = *(const bf16x8*)&sK[(32 + l31) * LSTR + c * 16 + h * 8];
      s0 = __builtin_amdgcn_mfma_f32_32x32x16_bf16(k0, qf[c], s0, 0, 0, 0);
      s1 = __builtin_amdgcn_mfma_f32_32x32x16_bf16(k1, qf[c], s1, 0, 0, 0);
    }

    // PV(t-1): P in lP (wave-private), V(t-1) in the OTHER KV buffer.
    if (kt > 0) {
      const bf16* pV = lKV[(kt + 1) & 1][1];
#pragma unroll
      for (int c = 0; c < 4; c++) {
        bf16x8 pf = *(const bf16x8*)&pw[l31 * LSTR + c * 16 + h * 8];
        bf16x8 v0 = *(const bf16x8*)&pV[l31 * LSTR + c * 16 + h * 8];
        bf16x8 v1 = *(const bf16x8*)&pV[(32 + l31) * LSTR + c * 16 + h * 8];
        o0 = __builtin_amdgcn_mfma_f32_32x32x16_bf16(v0, pf, o0, 0, 0, 0);
        o1 = __builtin_amdgcn_mfma_f32_32x32x16_bf16(v1, pf, o1, 0, 0, 0);
      }
    }

    // softmax(t) — overlaps the in-flight PV MFMAs (independent of o)
    float mx = -1e30f;
#pragma unroll
    for (int r = 0; r < 16; r++) { mx = fmaxf(mx, s0[r]); mx = fmaxf(mx, s1[r]); }
    mx = fmaxf(mx, __shfl_xor(mx, 32, 64));
    const float nm = fmaxf(mrow, mx);
    const float alpha = EXP2F(mrow - nm);
    mrow = nm;

    float rs = 0.f;
#pragma unroll
    for (int r = 0; r < 16; r++) {
      const float p0 = EXP2F(s0[r] - nm);
      const float p1 = EXP2F(s1[r] - nm);
      s0[r] = p0; s1[r] = p1;
      rs += p0 + p1;
    }
    rs += __shfl_xor(rs, 32, 64);
    lrow = lrow * alpha + rs;

    // o-rescale: must follow PV(t-1) completion (reg dependency enforces)
#pragma unroll
    for (int r = 0; r < 16; r++) { o0[r] *= alpha; o1[r] *= alpha; }

    // write P(t) for consumption at iter t+1 (wave-private, DS in-order)
#pragma unroll
    for (int g = 0; g < 4; g++) {
      bf16x4 pa = { (bf16)s0[4*g], (bf16)s0[4*g+1], (bf16)s0[4*g+2], (bf16)s0[4*g+3] };
      bf16x4 pb = { (bf16)s1[4*g], (bf16)s1[4*g+1], (bf16)s1[4*g+2], (bf16)s1[4*g+3] };
      *(bf16x4*)&pw[l31 * LSTR + g * 8 + h * 4]      = pa;
      *(bf16x4*)&pw[l31 * LSTR + 32 + g * 8 + h * 4] = pb;
    }
  }

  // drain: PV(31) from buf[31&1 = 1]
  {
    const bf16* pV = lKV[1][1];
#pragma unroll
    for (int c = 0; c < 4; c++) {
      bf16x8 pf = *(const bf16x8*)&pw[l31 * LSTR + c * 16 + h * 8];
      bf16x8 v0 = *(const bf16x8*)&pV[l31 * LSTR + c * 16 + h * 8];
      bf16x8 v1 = *(const bf16x8*)&pV[(32 + l31) * LSTR + c * 16 + h * 8];
      o0 = __builtin_amdgcn_mfma_f32_32x32x16_bf16(v0, pf, o0, 0, 0, 0);
      o1 = __builtin_amdgcn_mfma_f32_32x32x16_bf16(v1, pf, o1, 0, 0, 0);
    }
  }

  const int b = bh >> 4, head = bh & 15;
  const float inv = 1.f / lrow;
  const size_t base = ((size_t)b * SEQ + qrow) * DIMD + head * HDIM;
#pragma unroll
  for (int g = 0; g < 4; g++) {
    bf16x4 oa = { (bf16)(o0[4*g] * inv), (bf16)(o0[4*g+1] * inv),
                  (bf16)(o0[4*g+2] * inv), (bf16)(o0[4*g+3] * inv) };
    bf16x4 ob = { (bf16)(o1[4*g] * inv), (bf16)(o1[4*g+1] * inv),
                  (bf16)(o1[4*g+2] * inv), (bf16)(o1[4*g+3] * inv) };
    *(bf16x4*)&Ob[base + g * 8 + h * 4]      = oa;
    *(bf16x4*)&Ob[base + 32 + g * 8 + h * 4] = ob;
  }
}

extern "C" void kernel_launch(void* const* d_in, const int* in_sizes, int n_in,
                              void* d_out, int out_size, void* d_ws, size_t ws_size,
                              hipStream_t stream) {
  const float* x      = (const float*)d_in[0];
  const float* w_qkv  = (const float*)d_in[1];
  const float* b_qkv  = (const float*)d_in[2];
  const float* w_proj = (const float*)d_in[3];
  const float* b_proj = (const float*)d_in[4];
  float* out = (float*)d_out;
  char* ws = (char*)d_ws;

  bf16* Qb = (bf16*)d_out;
  bf16* Kb = (bf16*)d_out + (size_t)MTOT * DIMD;
  bf16* xb     = (bf16*)(ws + OFF_XB);
  bf16* Ob     = (bf16*)(ws + OFF_OB);   // overlays xb (dead after QKV GEMM)
  bf16* Vt     = (bf16*)(ws + OFF_VT);
  bf16* wprojb = (bf16*)(ws + OFF_WP);   // overlays Vt (dead after attn)

  cvt_kernel<<<(MTOT * DIMD / 4) / 256, 256, 0, stream>>>(x, xb, MTOT * DIMD / 4);
  gemm_qkv<<<dim3(24, 32), 256, 0, stream>>>(xb, w_qkv, b_qkv, Qb, Kb, Vt);
  attn_kernel<<<BATCH * NHEAD * (SEQ / 128), 256, 0, stream>>>(Qb, Kb, Vt, Ob);
  cvt_kernel<<<(DIMD * DIMD / 4) / 256, 256, 0, stream>>>(w_proj, wprojb, DIMD * DIMD / 4);
  gemm_proj<<<dim3(8, 64), 256, 0, stream>>>(Ob, wprojb, b_proj, out);
}